// Round 1
// baseline (105.038 us; speedup 1.0000x reference)
//
#include <hip/hip_runtime.h>
#include <math.h>

// Problem constants
#define BB   64
#define LL   4096
#define DKC  128
#define DVC  128
#define HC   4
#define DKLC 64
#define DVLC 128
#define RC   128
#define NSPLIT 16
#define CHUNK  (LL / NSPLIT)   // 256 rows per split

// ---------------------------------------------------------------------------
// Kernel 0: fold q[h][d] = sum_k Wq[h,k] * Wk[d,h,k]   (H*DK = 512 values)
// ---------------------------------------------------------------------------
__global__ __launch_bounds__(512) void k_foldq(const float* __restrict__ Wq,
                                               const float* __restrict__ Wk,
                                               float* __restrict__ q) {
    int t = threadIdx.x;            // 0..511
    int h = t >> 7;                 // 0..3
    int d = t & 127;                // 0..127
    float acc = 0.f;
#pragma unroll 8
    for (int k = 0; k < DKLC; ++k)
        acc += Wq[h * DKLC + k] * Wk[(d * HC + h) * DKLC + k];
    q[h * DKC + d] = acc;
}

// ---------------------------------------------------------------------------
// Kernel A: s[b,h,l] = mask[b,l] ? -inf : scale * dot(K[b,l,:], q[h,:])
// one thread per row l; q staged in LDS (broadcast reads, conflict-free)
// ---------------------------------------------------------------------------
__global__ __launch_bounds__(256) void k_qk(const float* __restrict__ K,
                                            const int*   __restrict__ mask,
                                            const float* __restrict__ q,
                                            float* __restrict__ s) {
    __shared__ float4 q4[HC][DKC / 4];   // 2 KB
    int t = threadIdx.x;
    if (t < HC * DKC / 4)
        ((float4*)q4)[t] = ((const float4*)q)[t];
    __syncthreads();

    long row = (long)blockIdx.x * 256 + t;       // [0, B*L)
    int b = (int)(row >> 12);
    int l = (int)(row & (LL - 1));

    const float4* k4 = (const float4*)K + row * (DKC / 4);
    float acc[HC] = {0.f, 0.f, 0.f, 0.f};
#pragma unroll 8
    for (int i = 0; i < DKC / 4; ++i) {
        float4 kv = k4[i];
#pragma unroll
        for (int h = 0; h < HC; ++h) {
            float4 qv = q4[h][i];
            acc[h] += kv.x * qv.x + kv.y * qv.y + kv.z * qv.z + kv.w * qv.w;
        }
    }
    bool m = mask[row] != 0;
    const float scale = 0.08838834764831844f;   // 1/sqrt(128)
#pragma unroll
    for (int h = 0; h < HC; ++h)
        s[((long)b * HC + h) * LL + l] = m ? -INFINITY : acc[h] * scale;
}

// ---------------------------------------------------------------------------
// Kernel B: in-place softmax over l for each (b,h) row of s (L = 4096)
// 256 threads, 16 values per thread held in registers
// ---------------------------------------------------------------------------
__global__ __launch_bounds__(256) void k_softmax(float* __restrict__ s) {
    float* row = s + (long)blockIdx.x * LL;
    int t = threadIdx.x;

    float4 v[4];
    float m = -INFINITY;
#pragma unroll
    for (int i = 0; i < 4; ++i) {
        v[i] = ((float4*)row)[i * 256 + t];
        m = fmaxf(m, fmaxf(fmaxf(v[i].x, v[i].y), fmaxf(v[i].z, v[i].w)));
    }

    __shared__ float redm[4];
    __shared__ float reds[4];
    // wave (64-lane) max reduce
#pragma unroll
    for (int off = 32; off; off >>= 1) m = fmaxf(m, __shfl_down(m, off));
    if ((t & 63) == 0) redm[t >> 6] = m;
    __syncthreads();
    m = fmaxf(fmaxf(redm[0], redm[1]), fmaxf(redm[2], redm[3]));

    float sum = 0.f;
#pragma unroll
    for (int i = 0; i < 4; ++i) {
        v[i].x = expf(v[i].x - m);
        v[i].y = expf(v[i].y - m);
        v[i].z = expf(v[i].z - m);
        v[i].w = expf(v[i].w - m);
        sum += v[i].x + v[i].y + v[i].z + v[i].w;
    }
#pragma unroll
    for (int off = 32; off; off >>= 1) sum += __shfl_down(sum, off);
    if ((t & 63) == 0) reds[t >> 6] = sum;
    __syncthreads();
    sum = reds[0] + reds[1] + reds[2] + reds[3];

    float inv = 1.f / sum;
#pragma unroll
    for (int i = 0; i < 4; ++i) {
        v[i].x *= inv; v[i].y *= inv; v[i].z *= inv; v[i].w *= inv;
        ((float4*)row)[i * 256 + t] = v[i];
    }
}

// ---------------------------------------------------------------------------
// Kernel C: partial WV[b,split,h,e] = sum_{l in chunk} w[b,h,l] * V[b,l,e]
// block = (b, split); 256 threads = 8 row-groups x 32 float4-columns
// ---------------------------------------------------------------------------
__global__ __launch_bounds__(256) void k_wv(const float* __restrict__ V,
                                            const float* __restrict__ w,
                                            float* __restrict__ part) {
    int b     = blockIdx.x >> 4;
    int split = blockIdx.x & (NSPLIT - 1);
    int l0    = split * CHUNK;
    int t     = threadIdx.x;

    __shared__ float wlds[HC][CHUNK];          // 4 KB
#pragma unroll
    for (int h = 0; h < HC; ++h)
        wlds[h][t] = w[((long)b * HC + h) * LL + l0 + t];
    __syncthreads();

    int rg = t >> 5;   // 0..7 row group
    int i4 = t & 31;   // float4 column

    float4 acc[HC];
#pragma unroll
    for (int h = 0; h < HC; ++h) acc[h] = make_float4(0.f, 0.f, 0.f, 0.f);

    const float4* v4 = (const float4*)(V + ((long)b * LL + l0) * DVC) + i4;
    for (int it = 0; it < CHUNK / 8; ++it) {   // 32 iterations
        int r = it * 8 + rg;
        float4 vv = v4[(long)r * (DVC / 4)];
#pragma unroll
        for (int h = 0; h < HC; ++h) {
            float wgt = wlds[h][r];
            acc[h].x += wgt * vv.x;
            acc[h].y += wgt * vv.y;
            acc[h].z += wgt * vv.z;
            acc[h].w += wgt * vv.w;
        }
    }

    // reduce over the 8 row groups
    __shared__ float4 red[8][32][HC];          // 16 KB
#pragma unroll
    for (int h = 0; h < HC; ++h) red[rg][i4][h] = acc[h];
    __syncthreads();
#pragma unroll
    for (int off = 4; off; off >>= 1) {
        if (rg < off) {
#pragma unroll
            for (int h = 0; h < HC; ++h) {
                float4 o = red[rg + off][i4][h];
                red[rg][i4][h].x += o.x;
                red[rg][i4][h].y += o.y;
                red[rg][i4][h].z += o.z;
                red[rg][i4][h].w += o.w;
            }
        }
        __syncthreads();
    }
    if (rg == 0) {
        float4* p4 = (float4*)part;
#pragma unroll
        for (int h = 0; h < HC; ++h)
            p4[(((long)b * NSPLIT + split) * HC + h) * (DVC / 4) + i4] = red[0][i4][h];
    }
}

// ---------------------------------------------------------------------------
// Kernel D: per-b epilogue: reduce partials -> WV; QKV = (1/L) WV*Wv; out = QKV*Wo
// ---------------------------------------------------------------------------
__global__ __launch_bounds__(256) void k_out(const float* __restrict__ part,
                                             const float* __restrict__ Wv,
                                             const float* __restrict__ Wo,
                                             float* __restrict__ out) {
    int b = blockIdx.x;
    int t = threadIdx.x;
    __shared__ float WV[HC * DVC];     // 512
    __shared__ float QKV[HC * DVLC];   // 512

    for (int j = t; j < HC * DVC; j += 256) {
        float a = 0.f;
#pragma unroll
        for (int sp = 0; sp < NSPLIT; ++sp)
            a += part[((long)b * NSPLIT + sp) * (HC * DVC) + j];
        WV[j] = a;
    }
    __syncthreads();

    for (int j = t; j < HC * DVLC; j += 256) {
        int h = j >> 7, vv = j & 127;
        float a = 0.f;
#pragma unroll 8
        for (int e = 0; e < DVC; ++e)
            a += WV[h * DVC + e] * Wv[(e * HC + h) * DVLC + vv];
        QKV[j] = a * (1.0f / LL);
    }
    __syncthreads();

    for (int r = t; r < RC; r += 256) {
        float a = 0.f;
#pragma unroll 8
        for (int i = 0; i < HC * DVLC; ++i)
            a += QKV[i] * Wo[i * RC + r];
        out[b * RC + r] = a;
    }
}

// ---------------------------------------------------------------------------
extern "C" void kernel_launch(void* const* d_in, const int* in_sizes, int n_in,
                              void* d_out, int out_size, void* d_ws, size_t ws_size,
                              hipStream_t stream) {
    (void)in_sizes; (void)n_in; (void)out_size; (void)ws_size;
    const float* K    = (const float*)d_in[0];
    const float* V    = (const float*)d_in[1];
    const int*   mask = (const int*)  d_in[2];
    const float* Wq   = (const float*)d_in[3];
    const float* Wk   = (const float*)d_in[4];
    const float* Wv   = (const float*)d_in[5];
    const float* Wo   = (const float*)d_in[6];
    float* out = (float*)d_out;

    float* q    = (float*)d_ws;                       // 512 floats
    float* s    = q + 512;                            // B*H*L = 1,048,576 floats
    float* part = s + (long)BB * HC * LL;             // B*NSPLIT*H*DV = 524,288 floats

    k_foldq<<<1, 512, 0, stream>>>(Wq, Wk, q);
    k_qk<<<BB * LL / 256, 256, 0, stream>>>(K, mask, q, s);
    k_softmax<<<BB * HC, 256, 0, stream>>>(s);
    k_wv<<<BB * NSPLIT, 256, 0, stream>>>(V, s, part);
    k_out<<<BB, 256, 0, stream>>>(part, Wv, Wo, out);
}

// Round 2
// 98.430 us; speedup vs baseline: 1.0671x; 1.0671x over previous
//
#include <hip/hip_runtime.h>
#include <math.h>

// Problem constants
#define BB   64
#define LL   4096
#define DKC  128
#define DVC  128
#define HC   4
#define DKLC 64
#define DVLC 128
#define RC   128
#define NSPLIT 16
#define CHUNK  (LL / NSPLIT)   // 256 rows per split

// ---------------------------------------------------------------------------
// Kernel 0: fold q[h][d] = sum_k Wq[h,k] * Wk[d,h,k]   (H*DK = 512 values)
// ---------------------------------------------------------------------------
__global__ __launch_bounds__(512) void k_foldq(const float* __restrict__ Wq,
                                               const float* __restrict__ Wk,
                                               float* __restrict__ q) {
    int t = threadIdx.x;            // 0..511
    int h = t >> 7;                 // 0..3
    int d = t & 127;                // 0..127
    float acc = 0.f;
#pragma unroll 8
    for (int k = 0; k < DKLC; ++k)
        acc += Wq[h * DKLC + k] * Wk[(d * HC + h) * DKLC + k];
    q[h * DKC + d] = acc;
}

// ---------------------------------------------------------------------------
// Fused kernel: per (b, split of 256 rows)
//   stage 1: scores s[h][r] = mask ? -inf : scale * dot(K[row], q[h])
//            (32 lanes per row -> contiguous 1 KB per wave, butterfly reduce)
//   stage 2: per-head chunk max m_p, P = exp(s - m_p), Z_p = sum P
//   stage 3: WVp[h][e] = sum_r P[h][r] * V[row][e]   (coalesced like old k_wv)
//   writes (m_p, Z_p) stats + WVp partials
// ---------------------------------------------------------------------------
__global__ __launch_bounds__(256) void k_fused(const float* __restrict__ K,
                                               const float* __restrict__ V,
                                               const int*   __restrict__ mask,
                                               const float* __restrict__ q,
                                               float* __restrict__ stats,
                                               float* __restrict__ part) {
    const int bid = blockIdx.x;
    const int b   = bid >> 4;
    const int sp  = bid & (NSPLIT - 1);
    const int l0  = sp * CHUNK;
    const int t   = threadIdx.x;
    const int i4  = t & 31;     // float4 column within a 128-float row
    const int rg  = t >> 5;     // 0..7 row group

    __shared__ float  P[HC][CHUNK];       // scores -> probabilities (4 KB)
    __shared__ float  wred[HC][2];        // per-head {m, Z}
    __shared__ float4 red[8][32][HC];     // stage-3 rowgroup reduce (16 KB)

    // q fragments in registers (each lane's float4 slice, all 4 heads)
    float4 qf[HC];
#pragma unroll
    for (int h = 0; h < HC; ++h)
        qf[h] = ((const float4*)(q + h * DKC))[i4];

    const float scale = 0.08838834764831844f;   // 1/sqrt(128)
    const float4* Kb = (const float4*)(K + ((long)b * LL + l0) * DKC);
    const int*    mb = mask + (long)b * LL + l0;

    // ---- Stage 1: scores (8 rows per iteration, one per 32-lane group) ----
#pragma unroll 4
    for (int it = 0; it < CHUNK / 8; ++it) {
        int r = it * 8 + rg;
        float4 kv = Kb[r * (DKC / 4) + i4];
        float d[HC];
#pragma unroll
        for (int h = 0; h < HC; ++h)
            d[h] = kv.x * qf[h].x + kv.y * qf[h].y + kv.z * qf[h].z + kv.w * qf[h].w;
        // reduce over the 32-lane group (xor offsets stay within the group)
#pragma unroll
        for (int off = 16; off; off >>= 1) {
#pragma unroll
            for (int h = 0; h < HC; ++h)
                d[h] += __shfl_xor(d[h], off);
        }
        if (i4 == 0) {
            bool msk = mb[r] != 0;
#pragma unroll
            for (int h = 0; h < HC; ++h)
                P[h][r] = msk ? -INFINITY : d[h] * scale;
        }
    }
    __syncthreads();

    // ---- Stage 2: per-head max + exp + sum (wave w owns head w) ----
    {
        int w    = t >> 6;      // 0..3 == head
        int lane = t & 63;
        float m = -INFINITY;
#pragma unroll
        for (int i = 0; i < CHUNK / 64; ++i)
            m = fmaxf(m, P[w][i * 64 + lane]);
#pragma unroll
        for (int off = 32; off; off >>= 1)
            m = fmaxf(m, __shfl_xor(m, off));
        // guard fully-masked chunk: use mu=0 so exp(-inf-0)=0 (no NaN)
        float mu = (m == -INFINITY) ? 0.f : m;
        float z = 0.f;
        float pv[CHUNK / 64];
#pragma unroll
        for (int i = 0; i < CHUNK / 64; ++i) {
            pv[i] = expf(P[w][i * 64 + lane] - mu);
            z += pv[i];
        }
#pragma unroll
        for (int i = 0; i < CHUNK / 64; ++i)
            P[w][i * 64 + lane] = pv[i];
#pragma unroll
        for (int off = 32; off; off >>= 1)
            z += __shfl_xor(z, off);
        if (lane == 0) { wred[w][0] = m; wred[w][1] = z; }
    }
    __syncthreads();

    if (t < HC) {
        stats[(long)bid * 8 + t]     = wred[t][0];   // raw max (may be -inf)
        stats[(long)bid * 8 + 4 + t] = wred[t][1];   // Z partial
    }

    // ---- Stage 3: WVp accumulation ----
    float4 acc[HC];
#pragma unroll
    for (int h = 0; h < HC; ++h) acc[h] = make_float4(0.f, 0.f, 0.f, 0.f);
    const float4* Vb = (const float4*)(V + ((long)b * LL + l0) * DVC);
#pragma unroll 4
    for (int it = 0; it < CHUNK / 8; ++it) {
        int r = it * 8 + rg;
        float4 vv = Vb[r * (DVC / 4) + i4];
#pragma unroll
        for (int h = 0; h < HC; ++h) {
            float wt = P[h][r];
            acc[h].x += wt * vv.x; acc[h].y += wt * vv.y;
            acc[h].z += wt * vv.z; acc[h].w += wt * vv.w;
        }
    }
#pragma unroll
    for (int h = 0; h < HC; ++h) red[rg][i4][h] = acc[h];
    __syncthreads();
#pragma unroll
    for (int off = 4; off; off >>= 1) {
        if (rg < off) {
#pragma unroll
            for (int h = 0; h < HC; ++h) {
                float4 o = red[rg + off][i4][h];
                red[rg][i4][h].x += o.x; red[rg][i4][h].y += o.y;
                red[rg][i4][h].z += o.z; red[rg][i4][h].w += o.w;
            }
        }
        __syncthreads();
    }
    if (rg == 0) {
        float4* p4 = (float4*)part;
#pragma unroll
        for (int h = 0; h < HC; ++h)
            p4[((long)bid * HC + h) * (DVC / 4) + i4] = red[0][i4][h];
    }
}

// ---------------------------------------------------------------------------
// Epilogue: combine split partials (softmax rescale), then
// QKV = (1/L) * WV*Wv ; out = QKV*Wo      one block per b
// ---------------------------------------------------------------------------
__global__ __launch_bounds__(256) void k_out(const float* __restrict__ stats,
                                             const float* __restrict__ part,
                                             const float* __restrict__ Wv,
                                             const float* __restrict__ Wo,
                                             float* __restrict__ out) {
    int b = blockIdx.x;
    int t = threadIdx.x;
    __shared__ float WV[HC][DVC];        // 2 KB
    __shared__ float QKV[HC * DVLC];     // 2 KB
    __shared__ float sc[NSPLIT][HC];     // rescale factors
    __shared__ float zs[HC];

    if (t < HC) {
        float m = -INFINITY;
        for (int p = 0; p < NSPLIT; ++p)
            m = fmaxf(m, stats[((long)b * NSPLIT + p) * 8 + t]);
        float Z = 0.f;
        for (int p = 0; p < NSPLIT; ++p) {
            float s = expf(stats[((long)b * NSPLIT + p) * 8 + t] - m);
            sc[p][t] = s;
            Z += s * stats[((long)b * NSPLIT + p) * 8 + 4 + t];
        }
        zs[t] = Z;
    }
    __syncthreads();

    for (int j = t; j < HC * DVC; j += 256) {
        int h = j >> 7, e = j & 127;
        float a = 0.f;
#pragma unroll
        for (int p = 0; p < NSPLIT; ++p)
            a += sc[p][h] * part[(((long)b * NSPLIT + p) * HC + h) * DVC + e];
        WV[h][e] = a / zs[h];
    }
    __syncthreads();

    for (int j = t; j < HC * DVLC; j += 256) {
        int h = j >> 7, vv = j & 127;
        float a = 0.f;
#pragma unroll 8
        for (int e = 0; e < DVC; ++e)
            a += WV[h][e] * Wv[(e * HC + h) * DVLC + vv];
        QKV[j] = a * (1.0f / LL);
    }
    __syncthreads();

    for (int r = t; r < RC; r += 256) {
        float a = 0.f;
#pragma unroll 8
        for (int i = 0; i < HC * DVLC; ++i)
            a += QKV[i] * Wo[i * RC + r];
        out[b * RC + r] = a;
    }
}

// ---------------------------------------------------------------------------
extern "C" void kernel_launch(void* const* d_in, const int* in_sizes, int n_in,
                              void* d_out, int out_size, void* d_ws, size_t ws_size,
                              hipStream_t stream) {
    (void)in_sizes; (void)n_in; (void)out_size; (void)ws_size;
    const float* K    = (const float*)d_in[0];
    const float* V    = (const float*)d_in[1];
    const int*   mask = (const int*)  d_in[2];
    const float* Wq   = (const float*)d_in[3];
    const float* Wk   = (const float*)d_in[4];
    const float* Wv   = (const float*)d_in[5];
    const float* Wo   = (const float*)d_in[6];
    float* out = (float*)d_out;

    float* q     = (float*)d_ws;                          // 512 floats
    float* stats = q + 512;                               // B*NSPLIT*8 = 8192
    float* part  = stats + (long)BB * NSPLIT * 8;         // B*NSPLIT*H*DV = 524288

    k_foldq<<<1, 512, 0, stream>>>(Wq, Wk, q);
    k_fused<<<BB * NSPLIT, 256, 0, stream>>>(K, V, mask, q, stats, part);
    k_out<<<BB, 256, 0, stream>>>(stats, part, Wv, Wo, out);
}